// Round 5
// baseline (87.608 us; speedup 1.0000x reference)
//
#include <hip/hip_runtime.h>

// y[32,8192] = x[32,8192] @ (A[8192,64] @ B[64,8192])^T + bias
// Factored: t = x @ B^T [32,64]; y = t @ A^T + bias.
// k1: split-K partials -> static __device__ scratch (verified R2/R4).
// k2: A read DIRECTLY to registers (thread-private: o = og*256+tid needs
//     exactly A4[o*16+r4]) -- removes the pointless 64 KB LDS round-trip,
//     barrier and swizzle ALU of the R4 version. b-groups widened 4->8
//     (grid 128): halves A fetch to 8 MB, reduce overlaps the A loads.
// Fixed harness floor (R2/R4 counters): unconditional 256 MiB ws poison fill
// (~40.6 us @ 82% HBM peak) + ~25 us of tiny reset dispatches. Kernels ~7 us.

#define BATCH 32
#define INF   8192
#define OUTF  8192
#define RANK  64
#define KCH   128            // K chunks; chunk = 8192/128 = 64 floats = 16 float4

__device__ float part_glob[KCH * BATCH * RANK];  // 1 MB static scratch, fully
                                                 // rewritten every launch before read

// ---------------- k1: part[c][32][64] = x[:,chunk_c] @ B[:,chunk_c]^T ----------
__global__ __launch_bounds__(256) void lr_k1(const float* __restrict__ x,
                                             const float* __restrict__ B) {
    const int c   = blockIdx.x;
    const int tid = threadIdx.x;

    __shared__ float4 xs[BATCH * 16];  // row-major, kk XOR-swizzled
    __shared__ float4 bs[RANK * 16];

    const float4* x4 = (const float4*)x;  // row stride 2048 f4
    const float4* b4 = (const float4*)B;

    // Stage x chunk: 512 f4, 2/thread. Global: 16 consecutive lanes read 16
    // consecutive f4 (256B segments). LDS write: permutation within a row -> no conflict.
#pragma unroll
    for (int it = 0; it < 2; ++it) {
        int gi = tid + it * 256, row = gi >> 4, kk = gi & 15;
        xs[row * 16 + (kk ^ (row & 15))] = x4[row * 2048 + c * 16 + kk];
    }
    // Stage B chunk: 1024 f4, 4/thread.
#pragma unroll
    for (int it = 0; it < 4; ++it) {
        int gi = tid + it * 256, row = gi >> 4, kk = gi & 15;
        bs[row * 16 + (kk ^ (row & 15))] = b4[row * 2048 + c * 16 + kk];
    }
    __syncthreads();

    // Thread tile: 2 batches x 4 ranks (ranks strided by 16 so per-instr lane
    // addresses land in distinct/2-way bank groups).
    const int bq = tid >> 4;   // b rows: bq*2, bq*2+1
    const int rr = tid & 15;   // r cols: rr + 16j

    float acc[2][4] = {};
#pragma unroll
    for (int kk = 0; kk < 16; ++kk) {
        float4 xa[2], bb[4];
#pragma unroll
        for (int i = 0; i < 2; ++i) {
            int row = bq * 2 + i;
            xa[i] = xs[row * 16 + (kk ^ (row & 15))];   // 4 distinct rows/wave -> free
        }
#pragma unroll
        for (int j = 0; j < 4; ++j) {
            int r = rr + 16 * j;
            bb[j] = bs[r * 16 + (kk ^ (r & 15))];       // 16 rows -> 2-way, free
        }
#pragma unroll
        for (int i = 0; i < 2; ++i)
#pragma unroll
            for (int j = 0; j < 4; ++j)
                acc[i][j] += xa[i].x * bb[j].x + xa[i].y * bb[j].y +
                             xa[i].z * bb[j].z + xa[i].w * bb[j].w;
    }

    // part[c][b][r], scalar stores: 16 consecutive lanes -> 64B contiguous.
#pragma unroll
    for (int i = 0; i < 2; ++i)
#pragma unroll
        for (int j = 0; j < 4; ++j)
            part_glob[c * 2048 + (bq * 2 + i) * 64 + 16 * j + rr] = acc[i][j];
}

// ---------------- k2: y = reduce(part) @ A^T + bias ----------------
// Grid: 32 o-groups x 4 b-groups = 128 blocks x 256 threads.
// Block: outputs og*256..+255, batches b0..b0+7.
__global__ __launch_bounds__(256) void lr_k2(const float* __restrict__ A,
                                             const float* __restrict__ bias,
                                             float* __restrict__ y) {
    const int og  = blockIdx.x >> 2;       // 0..31
    const int b0  = (blockIdx.x & 3) * 8;  // 0,8,16,24
    const int tid = threadIdx.x;

    __shared__ float4 red4[256];      // 4 KB reduce scratch
    __shared__ float4 ts4[128];       // reduced t rows b0..b0+7 ([b_local][r4])

    const int o = og * 256 + tid;

    // A is thread-private under this mapping: issue all 16 loads to REGISTERS
    // first so they pipeline under the part-reduce latency chain below. The
    // wave's 16 KB window (64 lanes x 256 B rows, contiguous in o) fits L1, so
    // every 64 B line is fully consumed across the r4 loop -> no overfetch.
    const float4* A4 = (const float4*)A;
    float4 a[16];
#pragma unroll
    for (int r4 = 0; r4 < 16; ++r4) a[r4] = A4[o * 16 + r4];
    const float bv = bias[o];

    // Vectorized reduce: block slice of part[c] is rows b0..b0+7 = 128 f4.
    // Thread (ch=tid>>7, e=tid&127) sums 64 f4 (c == ch mod 2), each wave load
    // 1 KB contiguous (coalesced, L2-resident).
    {
        const int ch = tid >> 7;   // c-group 0..1
        const int e  = tid & 127;  // f4 element within slice ([b_local][r4])
        const float4* p4 = (const float4*)part_glob;
        float4 s4 = {0.f, 0.f, 0.f, 0.f};
#pragma unroll 16
        for (int ci = 0; ci < KCH / 2; ++ci) {
            float4 v = p4[(ci * 2 + ch) * 512 + b0 * 16 + e];
            s4.x += v.x; s4.y += v.y; s4.z += v.z; s4.w += v.w;
        }
        red4[tid] = s4;
    }
    __syncthreads();

    // Combine the 2 c-group partials -> ts4[e], e=(b_local*16 + r4).
    if (tid < 128) {
        float4 a0 = red4[tid], a1 = red4[tid + 128];
        float4 r = {a0.x + a1.x, a0.y + a1.y, a0.z + a1.z, a0.w + a1.w};
        ts4[tid] = r;
    }
    __syncthreads();

    float accv[8] = {bv, bv, bv, bv, bv, bv, bv, bv};
#pragma unroll
    for (int r4 = 0; r4 < 16; ++r4) {
#pragma unroll
        for (int jb = 0; jb < 8; ++jb) {
            float4 tv = ts4[jb * 16 + r4];   // wave-uniform -> LDS broadcast, free
            accv[jb] += a[r4].x * tv.x + a[r4].y * tv.y +
                        a[r4].z * tv.z + a[r4].w * tv.w;
        }
    }

#pragma unroll
    for (int jb = 0; jb < 8; ++jb)
        y[(b0 + jb) * OUTF + o] = accv[jb];           // coalesced
}

extern "C" void kernel_launch(void* const* d_in, const int* in_sizes, int n_in,
                              void* d_out, int out_size, void* d_ws, size_t ws_size,
                              hipStream_t stream) {
    const float* x    = (const float*)d_in[0];   // [32, 8192]
    const float* A    = (const float*)d_in[1];   // [8192, 64]
    const float* B    = (const float*)d_in[2];   // [64, 8192]
    const float* bias = (const float*)d_in[3];   // [8192]
    float*       y    = (float*)d_out;           // [32, 8192]
    // d_ws unused; R2 counters proved the 256 MiB ws poison fill runs anyway,
    // so static __device__ scratch is equivalent but keeps us independent of
    // ws_size.

    lr_k1<<<KCH, 256, 0, stream>>>(x, B);
    lr_k2<<<128, 256, 0, stream>>>(A, bias, y);
}

// Round 6
// 72.682 us; speedup vs baseline: 1.2054x; 1.2054x over previous
//
#include <hip/hip_runtime.h>

// y[32,8192] = x[32,8192] @ (A[8192,64] @ B[64,8192])^T + bias
// Factored: t = x @ B^T [32,64]; y = t @ A^T + bias.
// k1: split-K partials -> static __device__ scratch.
// k2: vectorized per-block partial reduction (f4 x depth-32, 4-way wave split)
//     + LDS-staged A (the LDS round-trip IS the coalescing mechanism for A's
//     thread-private 256 B rows -- R5's direct-to-register variant regressed
//     +15 us from 64-way uncoalesced lane strides; do not repeat).
// Fixed harness floor (R2/R4/R5 counters): unconditional 256 MiB ws poison
// fill (~40.6 us @ 82% HBM peak, runs even with d_ws untouched) + ~25 us of
// tiny reset dispatches. Kernels ~7 us. This is the R4-verified 72.6 us build.

#define BATCH 32
#define INF   8192
#define OUTF  8192
#define RANK  64
#define KCH   128            // K chunks; chunk = 8192/128 = 64 floats = 16 float4

__device__ float part_glob[KCH * BATCH * RANK];  // 1 MB static scratch, fully
                                                 // rewritten every launch before read

// ---------------- k1: part[c][32][64] = x[:,chunk_c] @ B[:,chunk_c]^T ----------
__global__ __launch_bounds__(256) void lr_k1(const float* __restrict__ x,
                                             const float* __restrict__ B) {
    const int c   = blockIdx.x;
    const int tid = threadIdx.x;

    __shared__ float4 xs[BATCH * 16];  // row-major, kk XOR-swizzled
    __shared__ float4 bs[RANK * 16];

    const float4* x4 = (const float4*)x;  // row stride 2048 f4
    const float4* b4 = (const float4*)B;

    // Stage x chunk: 512 f4, 2/thread. Global: 16 consecutive lanes read 16
    // consecutive f4 (256B segments). LDS write: permutation within a row -> no conflict.
#pragma unroll
    for (int it = 0; it < 2; ++it) {
        int gi = tid + it * 256, row = gi >> 4, kk = gi & 15;
        xs[row * 16 + (kk ^ (row & 15))] = x4[row * 2048 + c * 16 + kk];
    }
    // Stage B chunk: 1024 f4, 4/thread.
#pragma unroll
    for (int it = 0; it < 4; ++it) {
        int gi = tid + it * 256, row = gi >> 4, kk = gi & 15;
        bs[row * 16 + (kk ^ (row & 15))] = b4[row * 2048 + c * 16 + kk];
    }
    __syncthreads();

    // Thread tile: 2 batches x 4 ranks (ranks strided by 16 so per-instr lane
    // addresses land in distinct/2-way bank groups).
    const int bq = tid >> 4;   // b rows: bq*2, bq*2+1
    const int rr = tid & 15;   // r cols: rr + 16j

    float acc[2][4] = {};
#pragma unroll
    for (int kk = 0; kk < 16; ++kk) {
        float4 xa[2], bb[4];
#pragma unroll
        for (int i = 0; i < 2; ++i) {
            int row = bq * 2 + i;
            xa[i] = xs[row * 16 + (kk ^ (row & 15))];   // 4 distinct rows/wave -> free
        }
#pragma unroll
        for (int j = 0; j < 4; ++j) {
            int r = rr + 16 * j;
            bb[j] = bs[r * 16 + (kk ^ (r & 15))];       // 16 rows -> 2-way, free
        }
#pragma unroll
        for (int i = 0; i < 2; ++i)
#pragma unroll
            for (int j = 0; j < 4; ++j)
                acc[i][j] += xa[i].x * bb[j].x + xa[i].y * bb[j].y +
                             xa[i].z * bb[j].z + xa[i].w * bb[j].w;
    }

    // part[c][b][r], scalar stores: 16 consecutive lanes -> 64B contiguous.
#pragma unroll
    for (int i = 0; i < 2; ++i)
#pragma unroll
        for (int j = 0; j < 4; ++j)
            part_glob[c * 2048 + (bq * 2 + i) * 64 + 16 * j + rr] = acc[i][j];
}

// ---------------- k2: y = reduce(part) @ A^T + bias ----------------
// Grid: 32 o-groups x 8 b-groups = 256 blocks x 256 threads.
// Block: outputs og*256..+255, batches b0..b0+3.
__global__ __launch_bounds__(256) void lr_k2(const float* __restrict__ A,
                                             const float* __restrict__ bias,
                                             float* __restrict__ y) {
    const int og  = blockIdx.x >> 3;       // 0..31
    const int b0  = (blockIdx.x & 7) * 4;  // 0..28
    const int tid = threadIdx.x;

    __shared__ float4 as[256 * 16];   // 64 KB A tile, XOR-swizzled
    __shared__ float4 red4[256];      // 4 KB reduce scratch
    __shared__ float4 ts4[64];        // reduced t rows b0..b0+3 ([b_local][r4])

    // Issue the A-tile stage FIRST so its 64 KB of global loads are in flight
    // under the partial-reduce latency chain below.
    // A4[(og*256+ol)*16 + r4] is 4096 consecutive f4 -> perfectly coalesced.
    // Swizzled store is a permutation within each 256B row -> no conflict.
    const float4* A4 = (const float4*)A;
#pragma unroll
    for (int it = 0; it < 16; ++it) {
        int gi = tid + it * 256, ol = gi >> 4, r4 = gi & 15;
        as[ol * 16 + (r4 ^ (ol & 15))] = A4[(og * 256 + ol) * 16 + r4];
    }

    // Vectorized reduce: block slice of part[c] is 64 f4 (1 KB). Wave w handles
    // chunks c ≡ w (mod 4): thread (cq=tid>>6, e=tid&63) sums 32 f4, each load
    // 1 KB contiguous per wave (perfectly coalesced, L2/L3-resident).
    {
        const int cq = tid >> 6;   // wave id 0..3
        const int e  = tid & 63;   // f4 element within slice
        const float4* p4 = (const float4*)part_glob;
        float4 s4 = {0.f, 0.f, 0.f, 0.f};
#pragma unroll 8
        for (int c8 = 0; c8 < KCH / 4; ++c8) {
            float4 v = p4[(c8 * 4 + cq) * 512 + b0 * 16 + e];
            s4.x += v.x; s4.y += v.y; s4.z += v.z; s4.w += v.w;
        }
        red4[tid] = s4;
    }
    __syncthreads();

    // Combine the 4 wave-partials -> ts4[e], e=(b_local*16 + r4).
    if (tid < 64) {
        float4 a0 = red4[tid], a1 = red4[tid + 64];
        float4 a2 = red4[tid + 128], a3 = red4[tid + 192];
        float4 r;
        r.x = (a0.x + a1.x) + (a2.x + a3.x);
        r.y = (a0.y + a1.y) + (a2.y + a3.y);
        r.z = (a0.z + a1.z) + (a2.z + a3.z);
        r.w = (a0.w + a1.w) + (a2.w + a3.w);
        ts4[tid] = r;
    }
    __syncthreads();

    const int o  = og * 256 + tid;
    const float bv = bias[o];
    float accv[4] = {bv, bv, bv, bv};

#pragma unroll
    for (int r4 = 0; r4 < 16; ++r4) {
        float4 a = as[tid * 16 + (r4 ^ (tid & 15))];  // 8 groups x 8 -> mild conflict
#pragma unroll
        for (int jb = 0; jb < 4; ++jb) {
            float4 tv = ts4[jb * 16 + r4];            // wave-uniform -> broadcast, free
            accv[jb] += a.x * tv.x + a.y * tv.y + a.z * tv.z + a.w * tv.w;
        }
    }

#pragma unroll
    for (int jb = 0; jb < 4; ++jb)
        y[(b0 + jb) * OUTF + o] = accv[jb];           // coalesced
}

extern "C" void kernel_launch(void* const* d_in, const int* in_sizes, int n_in,
                              void* d_out, int out_size, void* d_ws, size_t ws_size,
                              hipStream_t stream) {
    const float* x    = (const float*)d_in[0];   // [32, 8192]
    const float* A    = (const float*)d_in[1];   // [8192, 64]
    const float* B    = (const float*)d_in[2];   // [64, 8192]
    const float* bias = (const float*)d_in[3];   // [8192]
    float*       y    = (float*)d_out;           // [32, 8192]
    // d_ws unused; R2 counters proved the 256 MiB ws poison fill runs anyway,
    // so static __device__ scratch is equivalent but keeps us independent of
    // ws_size.

    lr_k1<<<KCH, 256, 0, stream>>>(x, B);
    lr_k2<<<256, 256, 0, stream>>>(A, bias, y);
}